// Round 8
// baseline (7375.325 us; speedup 1.0000x reference)
//
#include <hip/hip_runtime.h>

typedef _Float16 half8 __attribute__((ext_vector_type(8)));
typedef float float4v __attribute__((ext_vector_type(4)));
typedef unsigned long long u64;

#define TSEQ  1024
#define BATCH 128
#define HID   512
#define DIN   128

// LDS: per-wave gate scratch ONLY (h-tile staging eliminated in R8).
#define LDS_BYTES (4 * 8 * 32 * 4)           // 4096 B

// d_ws layout
#define WS_H16_OFF  0                                // [2][128][512] fp16 = 256 KiB
#define WS_BAR_OFF  (2 * BATCH * HID * 2)            // 262144
#define WS_XALL_OFF (1u << 20)                       // 1 MiB
#define WS_NEED     ((size_t)WS_XALL_OFF + (size_t)TSEQ * BATCH * DIN * 2)

struct U2 { u64 a, b; };

__device__ inline half8 cvt8(float4v a, float4v b) {
    half8 r;
    r[0] = (_Float16)a[0]; r[1] = (_Float16)a[1];
    r[2] = (_Float16)a[2]; r[3] = (_Float16)a[3];
    r[4] = (_Float16)b[0]; r[5] = (_Float16)b[1];
    r[6] = (_Float16)b[2]; r[7] = (_Float16)b[3];
    return r;
}

// branch-free sigmoid / tanh on v_exp_f32 + v_rcp_f32
__device__ inline float sigm(float x) {
    return __builtin_amdgcn_rcpf(1.0f + __builtin_amdgcn_exp2f(-1.44269504f * x));
}
__device__ inline float tanh_fast(float x) { return 2.0f * sigm(2.0f * x) - 1.0f; }

#define MF(A, B, C) __builtin_amdgcn_mfma_f32_16x16x32_f16((A), (B), (C), 0, 0, 0)

// 16 teams x 16 CUs. Team owns rows [8t,8t+8); CU p owns units [32p,32p+32);
// wave w owns units [..+8w..). Weights resident (VGPR/AGPR) fp16 all run.
// h handoff: RAW fp16, double-buffered, mantissa LSB = phase ((t>>1)&1)^1 —
// each 2-byte value self-describes freshness; relaxed AGENT atomics.
// [R1/R2/R4: never change the exchange scope. R5: keep 256 blocks.
//  R6: never early-issue poll loads. R7: publish coalescing is neutral.]
// R8: REGISTER-DIRECT h — the poll IS the MFMA fragment load. Each lane
// loads its A-fragment u64-pairs straight from h16 (agent scope, L1-bypass),
// validates via phase LSBs (tearing harmless: every 2B self-describes),
// retries per-kt, and feeds the MFMA chains directly. Eliminates the LDS
// h-tile, the ds_read pass, and the per-step __syncthreads (gate regroup is
// per-wave scratch). Waves fully decouple; skew stays <=1 step because a
// wave can only publish t after consuming all of h(t-1) (same dependency
// argument as the block-level protocol). 16 kt-fragments pipelined in 4
// groups of 4 with two register buffers: group g+1's loads fly under group
// g's check+MFMA.
// Poison 0xAAAA has LSB 0 != first expected phase 1 -> no init required.
template <bool XA>
__global__ __launch_bounds__(256, 1)
void lstm_persistent(const int* __restrict__ ids,
                     const int* __restrict__ seq_len,
                     const float* __restrict__ emb,
                     const float* __restrict__ w_ih,
                     const float* __restrict__ w_hh,
                     const float* __restrict__ b_ih,
                     const float* __restrict__ b_hh,
                     float* __restrict__ out,
                     _Float16* __restrict__ h16,      // [2][128][512] fp16
                     _Float16* __restrict__ x_all,    // [T][128][128] fp16
                     int* __restrict__ bar)
{
    __shared__ __align__(16) float gs[4 * 8 * 32];

    const int tid  = threadIdx.x;
    const int lane = tid & 63;
    const int wv   = tid >> 6;
    const int team = blockIdx.x & 15;
    const int p    = blockIdx.x >> 4;
    const int rowbase   = team * 8;
    const int unit_base = p * 32 + wv * 8;

    const int col  = lane & 15;   // MFMA n / C col
    const int kq   = lane >> 4;   // MFMA k-quad
    const int arow = lane & 7;    // A row (rows 8..15 duplicate 0..7)
    const int my_row  = lane >> 3;
    const int my_unit = unit_base + (lane & 7);

    if (XA) {
        // ---- phase 0: gather x_all[t][b][:] = fp16(emb[ids[t][b]][:]) ----
        for (int pair = blockIdx.x * 256 + tid; pair < TSEQ * BATCH;
             pair += 256 * 256) {
            const float* src = emb + (size_t)ids[pair] * DIN;   // pair = t*128+b
            _Float16* dst = x_all + (size_t)pair * DIN;
#pragma unroll
            for (int k = 0; k < 16; ++k) {
                float4v a = *(const float4v*)(src + k * 8);
                float4v c = *(const float4v*)(src + k * 8 + 4);
                *(half8*)(dst + k * 8) = cvt8(a, c);
            }
        }
        // ---- one-time grid barrier (full release/acquire, only here) ----
        __threadfence();
        __syncthreads();
        if (tid == 0) {
            __hip_atomic_fetch_add(bar, 1, __ATOMIC_RELEASE,
                                   __HIP_MEMORY_SCOPE_AGENT);
            int g = 0;
            while (__hip_atomic_load(bar, __ATOMIC_ACQUIRE,
                                     __HIP_MEMORY_SCOPE_AGENT) < 256
                   && ++g < (1 << 26)) { }
        }
        __syncthreads();
        __threadfence();
    }

    int tmax = 0, my_tstar = 0;
    for (int r = 0; r < 8; ++r) {
        int s  = seq_len[rowbase + r];
        int ts = (s > 0) ? (s - 1) : 0;
        if (r == my_row) my_tstar = ts;
        tmax = (ts > tmax) ? ts : tmax;
    }

    // ---- weight fragments -> registers (fp32 -> fp16), once ----
    const int wrow0 = (col & 3) * HID + unit_base + (col >> 2);
    const int wrow1 = (col & 3) * HID + unit_base + 4 + (col >> 2);
    const float bias0 = b_ih[wrow0] + b_hh[wrow0];
    const float bias1 = b_ih[wrow1] + b_hh[wrow1];

    half8 whhf0[16], whhf1[16];
#pragma unroll
    for (int kt = 0; kt < 16; ++kt) {
        const float* s0 = w_hh + (size_t)wrow0 * HID + kt * 32 + kq * 8;
        const float* s1 = w_hh + (size_t)wrow1 * HID + kt * 32 + kq * 8;
        whhf0[kt] = cvt8(*(const float4v*)s0, *(const float4v*)(s0 + 4));
        whhf1[kt] = cvt8(*(const float4v*)s1, *(const float4v*)(s1 + 4));
    }
    half8 wihf0[4], wihf1[4];
#pragma unroll
    for (int kt = 0; kt < 4; ++kt) {
        const float* s0 = w_ih + (size_t)wrow0 * DIN + kt * 32 + kq * 8;
        const float* s1 = w_ih + (size_t)wrow1 * DIN + kt * 32 + kq * 8;
        wihf0[kt] = cvt8(*(const float4v*)s0, *(const float4v*)(s0 + 4));
        wihf1[kt] = cvt8(*(const float4v*)s1, *(const float4v*)(s1 + 4));
    }

    float c_state = 0.0f;

    // ---- x fragment pipeline ----
    half8 xf[4], xn[4];
    if (XA) {
        const _Float16* x0 = x_all + ((size_t)0 * BATCH + rowbase + arow) * DIN;
        const int t1 = (tmax > 0) ? 1 : 0;
        const _Float16* x1 = x_all + ((size_t)t1 * BATCH + rowbase + arow) * DIN;
#pragma unroll
        for (int kt = 0; kt < 4; ++kt) {
            xf[kt] = *(const half8*)(x0 + kt * 32 + kq * 8);
            xn[kt] = *(const half8*)(x1 + kt * 32 + kq * 8);
        }
    } else {
        const int id0 = ids[rowbase + arow];
        const float* xrow = emb + (size_t)id0 * DIN;
#pragma unroll
        for (int kt = 0; kt < 4; ++kt) {
            const float* s = xrow + kt * 32 + kq * 8;
            xf[kt] = cvt8(*(const float4v*)s, *(const float4v*)(s + 4));
        }
    }

    // ---- acc(0) = bias + x(0) @ Wih, spread over 8 chains (a..d x 2) ----
    float4v a0 = {bias0, bias0, bias0, bias0}, b0 = {0,0,0,0}, c0 = {0,0,0,0}, d0 = {0,0,0,0};
    float4v a1 = {bias1, bias1, bias1, bias1}, b1 = {0,0,0,0}, c1 = {0,0,0,0}, d1 = {0,0,0,0};
    a0 = MF(xf[0], wihf0[0], a0);  b0 = MF(xf[1], wihf0[1], b0);
    c0 = MF(xf[2], wihf0[2], c0);  d0 = MF(xf[3], wihf0[3], d0);
    a1 = MF(xf[0], wihf1[0], a1);  b1 = MF(xf[1], wihf1[1], b1);
    c1 = MF(xf[2], wihf1[2], c1);  d1 = MF(xf[3], wihf1[3], d1);

    const u64 LSBM = 0x0001000100010001ull;
    int slp = 6;   // adaptive pre-poll delay, units of ~64 cyc

#define AL8(idx) __hip_atomic_load(hp + (idx), __ATOMIC_RELAXED, \
                                   __HIP_MEMORY_SCOPE_AGENT)
#define LDG(buf, g) \
    _Pragma("unroll") \
    for (int k2 = 0; k2 < 4; ++k2) { \
        buf[2*k2]   = AL8(((g)*4 + k2)*8 + ko); \
        buf[2*k2+1] = AL8(((g)*4 + k2)*8 + ko + 1); \
    }
#define PROC(buf, g) { \
    unsigned st = 0; \
    _Pragma("unroll") \
    for (int k2 = 0; k2 < 4; ++k2) \
        if ((((buf[2*k2] ^ want) | (buf[2*k2+1] ^ want)) & LSBM) != 0) \
            st |= 1u << k2; \
    if ((g) == 0) miss0 = st; \
    int round_ = 0, guard_ = 0; \
    while (__any((int)st)) { \
        _Pragma("unroll") \
        for (int k2 = 0; k2 < 4; ++k2) { \
            if (st & (1u << k2)) { \
                u64 lo_ = AL8(((g)*4 + k2)*8 + ko); \
                u64 hi_ = AL8(((g)*4 + k2)*8 + ko + 1); \
                if ((((lo_ ^ want) | (hi_ ^ want)) & LSBM) == 0) { \
                    buf[2*k2] = lo_; buf[2*k2+1] = hi_; st &= ~(1u << k2); \
                } \
            } \
        } \
        if (++round_ >= 3) __builtin_amdgcn_s_sleep(1); \
        if (++guard_ > (1 << 20)) break; \
    } \
    _Pragma("unroll") \
    for (int k2 = 0; k2 < 4; ++k2) { \
        const int kt = (g)*4 + k2; \
        U2 u2_; u2_.a = buf[2*k2]; u2_.b = buf[2*k2+1]; \
        const half8 af = __builtin_bit_cast(half8, u2_); \
        switch (k2) { \
        case 0: a0 = MF(af, whhf0[kt], a0); a1 = MF(af, whhf1[kt], a1); break; \
        case 1: b0 = MF(af, whhf0[kt], b0); b1 = MF(af, whhf1[kt], b1); break; \
        case 2: c0 = MF(af, whhf0[kt], c0); c1 = MF(af, whhf1[kt], c1); break; \
        default: d0 = MF(af, whhf0[kt], d0); d1 = MF(af, whhf1[kt], d1); \
        } \
    } }

    for (int t = 0; t <= tmax; ++t) {
        int id_next = 0;
        if (!XA) {
            const int tn = (t < tmax) ? (t + 1) : t;
            id_next = ids[tn * BATCH + rowbase + arow];
        }

        float4v xraw[8];
        if (!XA) {
            // issue emb(t+1) raw loads first: they fly under the h phase
            const float* xrow = emb + (size_t)id_next * DIN;
#pragma unroll
            for (int kt = 0; kt < 4; ++kt) {
                xraw[2 * kt]     = *(const float4v*)(xrow + kt * 32 + kq * 8);
                xraw[2 * kt + 1] = *(const float4v*)(xrow + kt * 32 + kq * 8 + 4);
            }
        }

        if (t > 0) {
            // ---- adaptive pre-poll delay (sample past producer visibility) ----
            for (int i = 0; i < slp; ++i) __builtin_amdgcn_s_sleep(1);

            // ---- register-direct h: load A-fragments straight from h16 ----
            const u64* hp = (const u64*)(h16
                + (size_t)((t + 1) & 1) * BATCH * HID + (rowbase + arow) * HID);
            const int ko = kq * 2;   // u64 offset inside a kt slot
            const u64 want = ((((t - 1) >> 1) & 1) ^ 1) ? LSBM : 0ull;
            unsigned miss0 = 0;
            u64 L0[8], L1[8];
            LDG(L0, 0);
            LDG(L1, 1);
            PROC(L0, 0);            // check+retry+MFMA kt 0..3 (G1 in flight)
            LDG(L0, 2);
            PROC(L1, 1);
            LDG(L1, 3);
            PROC(L0, 2);
            PROC(L1, 3);

            if (__any((int)miss0)) slp = (slp < 24) ? slp + 1 : 24;
            else                   slp = (slp > 1)  ? slp - 1 : 1;
        }

        const float4v g0 = (a0 + b0) + (c0 + d0);
        const float4v g1 = (a1 + b1) + (c1 + d1);

        // ---- regroup i,f,g,o per (row,unit) via per-wave LDS scratch ----
        float* gw = gs + wv * 256;
        if (lane < 32) {
            const int grow = (lane >> 4) * 4;
#pragma unroll
            for (int r = 0; r < 4; ++r) {
                gw[(grow + r) * 32 + col]      = g0[r];
                gw[(grow + r) * 32 + 16 + col] = g1[r];
            }
        }
        const float4v g4 = *(const float4v*)(gw + my_row * 32 + (lane & 7) * 4);

        const float i_s = sigm(g4[0]);
        const float f_s = sigm(g4[1]);
        const float g_t = tanh_fast(g4[2]);
        const float o_s = sigm(g4[3]);
        c_state = f_s * c_state + i_s * g_t;
        const float hn = o_s * tanh_fast(c_state);

        if (t == my_tstar)
            out[(rowbase + my_row) * HID + my_unit] = c_state;

        // ---- publish h: raw fp16, mantissa LSB = phase; fire-and-forget ----
        {
            const unsigned pub_phase = (((unsigned)t >> 1) & 1u) ^ 1u;
            unsigned short hb16 = __builtin_bit_cast(unsigned short, (_Float16)hn);
            hb16 = (unsigned short)((hb16 & 0xFFFEu) | pub_phase);
            __hip_atomic_store((unsigned short*)h16
                                   + (size_t)(t & 1) * BATCH * HID
                                   + (rowbase + my_row) * HID + my_unit,
                               hb16, __ATOMIC_RELAXED, __HIP_MEMORY_SCOPE_AGENT);
        }

        // ---- filler: x rotate/prefetch + x-MFMA(t+1) (visibility shadow) ----
        if (XA) {
#pragma unroll
            for (int kt = 0; kt < 4; ++kt) xf[kt] = xn[kt];
            const int t2 = (t + 2 <= tmax) ? (t + 2) : tmax;
            const _Float16* xs2 = x_all + ((size_t)t2 * BATCH + rowbase + arow) * DIN;
#pragma unroll
            for (int kt = 0; kt < 4; ++kt)
                xn[kt] = *(const half8*)(xs2 + kt * 32 + kq * 8);
        } else {
#pragma unroll
            for (int kt = 0; kt < 4; ++kt)
                xf[kt] = cvt8(xraw[2 * kt], xraw[2 * kt + 1]);
        }

        a0 = (float4v){bias0, bias0, bias0, bias0}; b0 = (float4v){0,0,0,0};
        c0 = (float4v){0,0,0,0};                    d0 = (float4v){0,0,0,0};
        a1 = (float4v){bias1, bias1, bias1, bias1}; b1 = (float4v){0,0,0,0};
        c1 = (float4v){0,0,0,0};                    d1 = (float4v){0,0,0,0};
        a0 = MF(xf[0], wihf0[0], a0);  b0 = MF(xf[1], wihf0[1], b0);
        c0 = MF(xf[2], wihf0[2], c0);  d0 = MF(xf[3], wihf0[3], d0);
        a1 = MF(xf[0], wihf1[0], a1);  b1 = MF(xf[1], wihf1[1], b1);
        c1 = MF(xf[2], wihf1[2], c1);  d1 = MF(xf[3], wihf1[3], d1);
    }
#undef AL8
#undef LDG
#undef PROC
}

extern "C" void kernel_launch(void* const* d_in, const int* in_sizes, int n_in,
                              void* d_out, int out_size, void* d_ws, size_t ws_size,
                              hipStream_t stream)
{
    const int*   ids  = (const int*)d_in[0];
    const int*   slen = (const int*)d_in[1];
    const float* emb  = (const float*)d_in[2];
    const float* wih  = (const float*)d_in[3];
    const float* whh  = (const float*)d_in[4];
    const float* bih  = (const float*)d_in[5];
    const float* bhh  = (const float*)d_in[6];
    float* out = (float*)d_out;

    _Float16* h16   = (_Float16*)((char*)d_ws + WS_H16_OFF);
    int*      bar   = (int*)((char*)d_ws + WS_BAR_OFF);
    _Float16* x_all = (_Float16*)((char*)d_ws + WS_XALL_OFF);

    if (ws_size >= WS_NEED) {
        hipMemsetAsync(bar, 0, sizeof(int), stream);
        hipLaunchKernelGGL((lstm_persistent<true>), dim3(256), dim3(256), 0, stream,
                           ids, slen, emb, wih, whh, bih, bhh, out,
                           h16, x_all, bar);
    } else {
        hipLaunchKernelGGL((lstm_persistent<false>), dim3(256), dim3(256), 0, stream,
                           ids, slen, emb, wih, whh, bih, bhh, out,
                           h16, x_all, bar);
    }
}

// Round 9
// 2153.186 us; speedup vs baseline: 3.4253x; 3.4253x over previous
//
#include <hip/hip_runtime.h>

typedef _Float16 half8 __attribute__((ext_vector_type(8)));
typedef float float4v __attribute__((ext_vector_type(4)));
typedef unsigned long long u64;

#define TSEQ  1024
#define BATCH 128
#define HID   512
#define DIN   128

// LDS: double-buffered h tile. Row stride 264 b32-words (528 halves) so the
// MFMA ds_read_b128 pattern lands 2-way max (free).
#define HW_STRIDE 264                        // b32 words per row
#define HBUF_WORDS (8 * HW_STRIDE)           // 2112 words per buffer
#define GOFF (2 * HBUF_WORDS * 4)            // 16896 B
#define LDS_BYTES (GOFF + 4 * 8 * 32 * 4)    // + per-wave gate scratch = 20992 B

// d_ws layout
#define WS_H16_OFF  0                                // [2][128][512] fp16 = 256 KiB
#define WS_BAR_OFF  (2 * BATCH * HID * 2)            // 262144
#define WS_XALL_OFF (1u << 20)                       // 1 MiB
#define WS_NEED     ((size_t)WS_XALL_OFF + (size_t)TSEQ * BATCH * DIN * 2)

__device__ inline half8 cvt8(float4v a, float4v b) {
    half8 r;
    r[0] = (_Float16)a[0]; r[1] = (_Float16)a[1];
    r[2] = (_Float16)a[2]; r[3] = (_Float16)a[3];
    r[4] = (_Float16)b[0]; r[5] = (_Float16)b[1];
    r[6] = (_Float16)b[2]; r[7] = (_Float16)b[3];
    return r;
}

// branch-free sigmoid / tanh on v_exp_f32 + v_rcp_f32
__device__ inline float sigm(float x) {
    return __builtin_amdgcn_rcpf(1.0f + __builtin_amdgcn_exp2f(-1.44269504f * x));
}
__device__ inline float tanh_fast(float x) { return 2.0f * sigm(2.0f * x) - 1.0f; }

// 16 teams x 16 CUs. Team owns rows [8t,8t+8); CU p owns units [32p,32p+32);
// wave w owns units [..+8w..). Weights VGPR-resident fp16 for the whole run.
// h handoff: RAW fp16, double-buffered, with the mantissa LSB carrying a
// phase bit ((t>>1)&1)^1 — each 2-byte value self-describes freshness, so
// relaxed AGENT atomics suffice and the exchange tile is 8 KB (untagged).
// [Session ledger: R1/R2/R4 sc0/L2-scope variants starve or regress — agent
//  scope everywhere. R5 dual-team loses 2x CUs. R6 early-issue samples too
//  early (value is fixed at SERVICE time). R7 publish coalescing neutral.
//  R8 register-direct h amplifies load requests 8x — block-cooperative LDS
//  staging is the right exchange granularity.]
// Poison 0xAAAA has LSB 0 != first expected phase 1 -> no init required.
// Step: poll(h(t-1)) -> barrier -> h-MFMAs (8 chains) -> gates -> publish ->
// filler (x rotate/prefetch + x-MFMA(t+1)) -> s_sleep(6) -> loop.
// R9 change: STAGGERED MULTI-SAMPLE retry. Each retry round issues TWO
// loads per pending word ~128cyc apart (sched_barrier-pinned so the relaxed
// atomics can't merge), then checks oldest->newest. A publish landing at
// t+x is now caught at granularity ~128cyc within a round instead of a full
// serial ~850cyc RT per sample — halves the RT-quantization of the miss
// tail that no fixed pre-poll delay can remove (R7 evidence: jitter).
template <bool XA>
__global__ __launch_bounds__(256, 1)
void lstm_persistent(const int* __restrict__ ids,
                     const int* __restrict__ seq_len,
                     const float* __restrict__ emb,
                     const float* __restrict__ w_ih,
                     const float* __restrict__ w_hh,
                     const float* __restrict__ b_ih,
                     const float* __restrict__ b_hh,
                     float* __restrict__ out,
                     _Float16* __restrict__ h16,      // [2][128][512] fp16
                     _Float16* __restrict__ x_all,    // [T][128][128] fp16
                     int* __restrict__ bar)
{
    __shared__ __align__(16) char smem[LDS_BYTES];
    unsigned* hsu = (unsigned*)smem;
    _Float16* hsh = (_Float16*)smem;
    float*    gs  = (float*)(smem + GOFF);

    const int tid  = threadIdx.x;
    const int lane = tid & 63;
    const int wv   = tid >> 6;
    const int team = blockIdx.x & 15;
    const int p    = blockIdx.x >> 4;
    const int rowbase   = team * 8;
    const int unit_base = p * 32 + wv * 8;

    const int col  = lane & 15;   // MFMA n / C col
    const int kq   = lane >> 4;   // MFMA k-quad
    const int arow = lane & 7;    // A row (rows 8..15 duplicate 0..7)
    const int my_row  = lane >> 3;
    const int my_unit = unit_base + (lane & 7);

    if (XA) {
        // ---- phase 0: gather x_all[t][b][:] = fp16(emb[ids[t][b]][:]) ----
        for (int pair = blockIdx.x * 256 + tid; pair < TSEQ * BATCH;
             pair += 256 * 256) {
            const float* src = emb + (size_t)ids[pair] * DIN;   // pair = t*128+b
            _Float16* dst = x_all + (size_t)pair * DIN;
#pragma unroll
            for (int k = 0; k < 16; ++k) {
                float4v a = *(const float4v*)(src + k * 8);
                float4v c = *(const float4v*)(src + k * 8 + 4);
                *(half8*)(dst + k * 8) = cvt8(a, c);
            }
        }
        // ---- one-time grid barrier (full release/acquire, only here) ----
        __threadfence();
        __syncthreads();
        if (tid == 0) {
            __hip_atomic_fetch_add(bar, 1, __ATOMIC_RELEASE,
                                   __HIP_MEMORY_SCOPE_AGENT);
            int g = 0;
            while (__hip_atomic_load(bar, __ATOMIC_ACQUIRE,
                                     __HIP_MEMORY_SCOPE_AGENT) < 256
                   && ++g < (1 << 26)) { }
        }
        __syncthreads();
        __threadfence();
    }

    int tmax = 0, my_tstar = 0;
    for (int r = 0; r < 8; ++r) {
        int s  = seq_len[rowbase + r];
        int ts = (s > 0) ? (s - 1) : 0;
        if (r == my_row) my_tstar = ts;
        tmax = (ts > tmax) ? ts : tmax;
    }

    // ---- weight fragments -> VGPRs (fp32 -> fp16), once ----
    const int wrow0 = (col & 3) * HID + unit_base + (col >> 2);
    const int wrow1 = (col & 3) * HID + unit_base + 4 + (col >> 2);
    const float bias0 = b_ih[wrow0] + b_hh[wrow0];
    const float bias1 = b_ih[wrow1] + b_hh[wrow1];

    half8 whhf0[16], whhf1[16];
#pragma unroll
    for (int kt = 0; kt < 16; ++kt) {
        const float* s0 = w_hh + (size_t)wrow0 * HID + kt * 32 + kq * 8;
        const float* s1 = w_hh + (size_t)wrow1 * HID + kt * 32 + kq * 8;
        whhf0[kt] = cvt8(*(const float4v*)s0, *(const float4v*)(s0 + 4));
        whhf1[kt] = cvt8(*(const float4v*)s1, *(const float4v*)(s1 + 4));
    }
    half8 wihf0[4], wihf1[4];
#pragma unroll
    for (int kt = 0; kt < 4; ++kt) {
        const float* s0 = w_ih + (size_t)wrow0 * DIN + kt * 32 + kq * 8;
        const float* s1 = w_ih + (size_t)wrow1 * DIN + kt * 32 + kq * 8;
        wihf0[kt] = cvt8(*(const float4v*)s0, *(const float4v*)(s0 + 4));
        wihf1[kt] = cvt8(*(const float4v*)s1, *(const float4v*)(s1 + 4));
    }

    float c_state = 0.0f;
    const int crow = tid >> 5;    // poll/staging: row 0..7, 32 threads/row
    const int coff = tid & 31;    // thread polls u64s {coff + 32j}, j=0..3

    // ---- x fragment pipeline ----
    half8 xf[4], xn[4];
    if (XA) {
        const _Float16* x0 = x_all + ((size_t)0 * BATCH + rowbase + arow) * DIN;
        const int t1 = (tmax > 0) ? 1 : 0;
        const _Float16* x1 = x_all + ((size_t)t1 * BATCH + rowbase + arow) * DIN;
#pragma unroll
        for (int kt = 0; kt < 4; ++kt) {
            xf[kt] = *(const half8*)(x0 + kt * 32 + kq * 8);
            xn[kt] = *(const half8*)(x1 + kt * 32 + kq * 8);
        }
    } else {
        const int id0 = ids[rowbase + arow];
        const float* xrow = emb + (size_t)id0 * DIN;
#pragma unroll
        for (int kt = 0; kt < 4; ++kt) {
            const float* s = xrow + kt * 32 + kq * 8;
            xf[kt] = cvt8(*(const float4v*)s, *(const float4v*)(s + 4));
        }
    }

    // ---- acc(0) = bias + x(0) @ Wih, spread over 8 chains (a..d x 2) ----
    float4v a0 = {bias0, bias0, bias0, bias0}, b0 = {0,0,0,0}, c0 = {0,0,0,0}, d0 = {0,0,0,0};
    float4v a1 = {bias1, bias1, bias1, bias1}, b1 = {0,0,0,0}, c1 = {0,0,0,0}, d1 = {0,0,0,0};
    a0 = __builtin_amdgcn_mfma_f32_16x16x32_f16(xf[0], wihf0[0], a0, 0, 0, 0);
    b0 = __builtin_amdgcn_mfma_f32_16x16x32_f16(xf[1], wihf0[1], b0, 0, 0, 0);
    c0 = __builtin_amdgcn_mfma_f32_16x16x32_f16(xf[2], wihf0[2], c0, 0, 0, 0);
    d0 = __builtin_amdgcn_mfma_f32_16x16x32_f16(xf[3], wihf0[3], d0, 0, 0, 0);
    a1 = __builtin_amdgcn_mfma_f32_16x16x32_f16(xf[0], wihf1[0], a1, 0, 0, 0);
    b1 = __builtin_amdgcn_mfma_f32_16x16x32_f16(xf[1], wihf1[1], b1, 0, 0, 0);
    c1 = __builtin_amdgcn_mfma_f32_16x16x32_f16(xf[2], wihf1[2], c1, 0, 0, 0);
    d1 = __builtin_amdgcn_mfma_f32_16x16x32_f16(xf[3], wihf1[3], d1, 0, 0, 0);

    const u64 LSBM = 0x0001000100010001ull;

    for (int t = 0; t <= tmax; ++t) {
        const int bs = t & 1;    // LDS h-tile buffer for this step
        int id_next = 0;
        if (!XA) {
            const int tn = (t < tmax) ? (t + 1) : t;
            id_next = ids[tn * BATCH + rowbase + arow];
        }

        if (t > 0) {
            // ---- poll teammates' phase-tagged fp16 h (poll IS the load) ----
            const u64* rowp = (const u64*)(h16
                + (size_t)((t + 1) & 1) * BATCH * HID + (rowbase + crow) * HID);
            const u64 want = ((((t - 1) >> 1) & 1) ^ 1) ? LSBM : 0ull;
            unsigned* dstw = hsu + bs * HBUF_WORDS + crow * HW_STRIDE + 2 * coff;
            u64 v[4];
            unsigned pending = 0xF;
#pragma unroll
            for (int j = 0; j < 4; ++j)
                v[j] = __hip_atomic_load(rowp + coff + 32 * j,
                                         __ATOMIC_RELAXED, __HIP_MEMORY_SCOPE_AGENT);
#pragma unroll
            for (int j = 0; j < 4; ++j) {
                if (((v[j] ^ want) & LSBM) == 0) {
                    *(u64*)(dstw + 64 * j) = v[j];
                    pending &= ~(1u << j);
                }
            }
            // ---- staggered multi-sample retry: 2 samples/round ~128cyc
            //      apart; check oldest->newest (newest costs only the
            //      incremental wait, not a fresh RT) ----
            int round = 0, guard = 0;
            while (pending) {
                u64 y0[4], y1[4];
#pragma unroll
                for (int j = 0; j < 4; ++j)
                    if (pending & (1u << j))
                        y0[j] = __hip_atomic_load(rowp + coff + 32 * j,
                                                  __ATOMIC_RELAXED,
                                                  __HIP_MEMORY_SCOPE_AGENT);
                __builtin_amdgcn_sched_barrier(0);
                __builtin_amdgcn_s_sleep(2);          // ~128 cyc issue stagger
                __builtin_amdgcn_sched_barrier(0);
#pragma unroll
                for (int j = 0; j < 4; ++j)
                    if (pending & (1u << j))
                        y1[j] = __hip_atomic_load(rowp + coff + 32 * j,
                                                  __ATOMIC_RELAXED,
                                                  __HIP_MEMORY_SCOPE_AGENT);
#pragma unroll
                for (int j = 0; j < 4; ++j) {
                    if (pending & (1u << j)) {
                        if (((y0[j] ^ want) & LSBM) == 0) {
                            *(u64*)(dstw + 64 * j) = y0[j];
                            pending &= ~(1u << j);
                        } else if (((y1[j] ^ want) & LSBM) == 0) {
                            *(u64*)(dstw + 64 * j) = y1[j];
                            pending &= ~(1u << j);
                        }
                    }
                }
                if (!pending) break;
                if (++round >= 2) __builtin_amdgcn_s_sleep(2);
                if (++guard > (1 << 19)) break;   // anti-hang safety valve
            }
        }
        __syncthreads();   // the ONLY barrier per step (h-tile double-buffered)

        float4v xraw[8];
        if (!XA) {
            // fallback: issue emb(t+1) raw loads here (h-MFMA shadow)
            const float* xrow = emb + (size_t)id_next * DIN;
#pragma unroll
            for (int kt = 0; kt < 4; ++kt) {
                xraw[2 * kt]     = *(const float4v*)(xrow + kt * 32 + kq * 8);
                xraw[2 * kt + 1] = *(const float4v*)(xrow + kt * 32 + kq * 8 + 4);
            }
        }

        if (t > 0) {
            // ---- h MFMAs: 16 kt over 8 chains (dependent depth 4) ----
            const _Float16* hb = hsh + bs * HBUF_WORDS * 2;
#pragma unroll
            for (int kt = 0; kt < 16; ++kt) {
                half8 af = *(const half8*)(hb + arow * (HW_STRIDE * 2) + kt * 32 + kq * 8);
                switch (kt & 3) {
                case 0:
                    a0 = __builtin_amdgcn_mfma_f32_16x16x32_f16(af, whhf0[kt], a0, 0, 0, 0);
                    a1 = __builtin_amdgcn_mfma_f32_16x16x32_f16(af, whhf1[kt], a1, 0, 0, 0);
                    break;
                case 1:
                    b0 = __builtin_amdgcn_mfma_f32_16x16x32_f16(af, whhf0[kt], b0, 0, 0, 0);
                    b1 = __builtin_amdgcn_mfma_f32_16x16x32_f16(af, whhf1[kt], b1, 0, 0, 0);
                    break;
                case 2:
                    c0 = __builtin_amdgcn_mfma_f32_16x16x32_f16(af, whhf0[kt], c0, 0, 0, 0);
                    c1 = __builtin_amdgcn_mfma_f32_16x16x32_f16(af, whhf1[kt], c1, 0, 0, 0);
                    break;
                default:
                    d0 = __builtin_amdgcn_mfma_f32_16x16x32_f16(af, whhf0[kt], d0, 0, 0, 0);
                    d1 = __builtin_amdgcn_mfma_f32_16x16x32_f16(af, whhf1[kt], d1, 0, 0, 0);
                }
            }
        }
        const float4v g0 = (a0 + b0) + (c0 + d0);
        const float4v g1 = (a1 + b1) + (c1 + d1);

        // ---- regroup i,f,g,o per (row,unit) via per-wave LDS scratch ----
        float* gw = gs + wv * 256;
        if (lane < 32) {
            const int grow = (lane >> 4) * 4;
#pragma unroll
            for (int r = 0; r < 4; ++r) {
                gw[(grow + r) * 32 + col]      = g0[r];
                gw[(grow + r) * 32 + 16 + col] = g1[r];
            }
        }
        const float4v g4 = *(const float4v*)(gw + my_row * 32 + (lane & 7) * 4);

        const float i_s = sigm(g4[0]);
        const float f_s = sigm(g4[1]);
        const float g_t = tanh_fast(g4[2]);
        const float o_s = sigm(g4[3]);
        c_state = f_s * c_state + i_s * g_t;
        const float hn = o_s * tanh_fast(c_state);

        if (t == my_tstar)
            out[(rowbase + my_row) * HID + my_unit] = c_state;

        // ---- publish h: raw fp16, mantissa LSB = phase; fire-and-forget ----
        {
            const unsigned pub_phase = (((unsigned)t >> 1) & 1u) ^ 1u;
            unsigned short hb16 = __builtin_bit_cast(unsigned short, (_Float16)hn);
            hb16 = (unsigned short)((hb16 & 0xFFFEu) | pub_phase);
            __hip_atomic_store((unsigned short*)h16
                                   + (size_t)(t & 1) * BATCH * HID
                                   + (rowbase + my_row) * HID + my_unit,
                               hb16, __ATOMIC_RELAXED, __HIP_MEMORY_SCOPE_AGENT);
        }

        // ---- filler between publish and next poll: x pipeline + x-MFMA(t+1)
        //      then a tuned s_sleep so poll round-0 samples the IF *after*
        //      producer visibility ----
        if (XA) {
#pragma unroll
            for (int kt = 0; kt < 4; ++kt) xf[kt] = xn[kt];
            const int t2 = (t + 2 <= tmax) ? (t + 2) : tmax;
            const _Float16* xs2 = x_all + ((size_t)t2 * BATCH + rowbase + arow) * DIN;
#pragma unroll
            for (int kt = 0; kt < 4; ++kt)
                xn[kt] = *(const half8*)(xs2 + kt * 32 + kq * 8);
        } else {
#pragma unroll
            for (int kt = 0; kt < 4; ++kt)
                xf[kt] = cvt8(xraw[2 * kt], xraw[2 * kt + 1]);
        }

        a0 = (float4v){bias0, bias0, bias0, bias0}; b0 = (float4v){0,0,0,0};
        c0 = (float4v){0,0,0,0};                    d0 = (float4v){0,0,0,0};
        a1 = (float4v){bias1, bias1, bias1, bias1}; b1 = (float4v){0,0,0,0};
        c1 = (float4v){0,0,0,0};                    d1 = (float4v){0,0,0,0};
        a0 = __builtin_amdgcn_mfma_f32_16x16x32_f16(xf[0], wihf0[0], a0, 0, 0, 0);
        b0 = __builtin_amdgcn_mfma_f32_16x16x32_f16(xf[1], wihf0[1], b0, 0, 0, 0);
        c0 = __builtin_amdgcn_mfma_f32_16x16x32_f16(xf[2], wihf0[2], c0, 0, 0, 0);
        d0 = __builtin_amdgcn_mfma_f32_16x16x32_f16(xf[3], wihf0[3], d0, 0, 0, 0);
        a1 = __builtin_amdgcn_mfma_f32_16x16x32_f16(xf[0], wihf1[0], a1, 0, 0, 0);
        b1 = __builtin_amdgcn_mfma_f32_16x16x32_f16(xf[1], wihf1[1], b1, 0, 0, 0);
        c1 = __builtin_amdgcn_mfma_f32_16x16x32_f16(xf[2], wihf1[2], c1, 0, 0, 0);
        d1 = __builtin_amdgcn_mfma_f32_16x16x32_f16(xf[3], wihf1[3], d1, 0, 0, 0);

        // tuned pre-poll delay: ~384 cyc (producer store->IF visibility + skew)
        __builtin_amdgcn_s_sleep(6);
    }
}

extern "C" void kernel_launch(void* const* d_in, const int* in_sizes, int n_in,
                              void* d_out, int out_size, void* d_ws, size_t ws_size,
                              hipStream_t stream)
{
    const int*   ids  = (const int*)d_in[0];
    const int*   slen = (const int*)d_in[1];
    const float* emb  = (const float*)d_in[2];
    const float* wih  = (const float*)d_in[3];
    const float* whh  = (const float*)d_in[4];
    const float* bih  = (const float*)d_in[5];
    const float* bhh  = (const float*)d_in[6];
    float* out = (float*)d_out;

    _Float16* h16   = (_Float16*)((char*)d_ws + WS_H16_OFF);
    int*      bar   = (int*)((char*)d_ws + WS_BAR_OFF);
    _Float16* x_all = (_Float16*)((char*)d_ws + WS_XALL_OFF);

    if (ws_size >= WS_NEED) {
        hipMemsetAsync(bar, 0, sizeof(int), stream);
        hipLaunchKernelGGL((lstm_persistent<true>), dim3(256), dim3(256), 0, stream,
                           ids, slen, emb, wih, whh, bih, bhh, out,
                           h16, x_all, bar);
    } else {
        hipLaunchKernelGGL((lstm_persistent<false>), dim3(256), dim3(256), 0, stream,
                           ids, slen, emb, wih, whh, bih, bhh, out,
                           h16, x_all, bar);
    }
}

// Round 10
// 1853.776 us; speedup vs baseline: 3.9785x; 1.1615x over previous
//
#include <hip/hip_runtime.h>

typedef _Float16 half8 __attribute__((ext_vector_type(8)));
typedef float float4v __attribute__((ext_vector_type(4)));
typedef unsigned long long u64;

#define TSEQ  1024
#define BATCH 128
#define HID   512
#define DIN   128

// LDS: double-buffered h tile. Row stride 264 b32-words (528 halves) so the
// MFMA ds_read_b128 pattern lands 2-way max (free).
#define HW_STRIDE 264                        // b32 words per row
#define HBUF_WORDS (8 * HW_STRIDE)           // 2112 words per buffer
#define GOFF (2 * HBUF_WORDS * 4)            // 16896 B
#define PUB_OFF (GOFF + 4 * 8 * 32 * 4)      // gate scratch ends here
#define LDS_BYTES (PUB_OFF + 512)            // + 8x32 fp16 publish tile

// d_ws layout
#define WS_H16_OFF  0                                // [2][128][512] fp16 = 256 KiB
#define WS_BAR_OFF  (2 * BATCH * HID * 2)            // 262144
#define WS_XALL_OFF (1u << 20)                       // 1 MiB
#define WS_NEED     ((size_t)WS_XALL_OFF + (size_t)TSEQ * BATCH * DIN * 2)

__device__ inline half8 cvt8(float4v a, float4v b) {
    half8 r;
    r[0] = (_Float16)a[0]; r[1] = (_Float16)a[1];
    r[2] = (_Float16)a[2]; r[3] = (_Float16)a[3];
    r[4] = (_Float16)b[0]; r[5] = (_Float16)b[1];
    r[6] = (_Float16)b[2]; r[7] = (_Float16)b[3];
    return r;
}

// branch-free sigmoid / tanh on v_exp_f32 + v_rcp_f32
__device__ inline float sigm(float x) {
    return __builtin_amdgcn_rcpf(1.0f + __builtin_amdgcn_exp2f(-1.44269504f * x));
}
__device__ inline float tanh_fast(float x) { return 2.0f * sigm(2.0f * x) - 1.0f; }

// 16 teams x 16 CUs. Team owns rows [8t,8t+8); CU p owns units [32p,32p+32);
// wave w owns units [..+8w..). Weights VGPR-resident fp16 for the whole run.
// h handoff: RAW fp16, double-buffered, mantissa LSB = phase ((t>>1)&1)^1 —
// each 2-byte value self-describes freshness; relaxed AGENT atomics.
// [Session ledger: R1/R2/R4 scope variants starve/regress — agent scope
//  everywhere. R5 dual-team loses 2x CUs. R6 early-issue samples too early.
//  R7 row-coalescing neutral (didn't change per-sector event count).
//  R8 register-direct h amplifies requests 8x. R9 multi-sample retry
//  neutral — each retry is a full RT regardless of sampling density.]
// COUNTER MODEL (from FETCH_SIZE ~= one h16 working set per step): agent
// stores write-through and INVALIDATE the L2 line; consumer polls are
// L2-served; each store EVENT to a sector forces a consumer refetch
// (~900cyc). A 64B sector (one row x one CU's 32 units) previously took 4
// partial 16B stores (one per wave) -> up to 4 invalidate/refetch rounds.
// R10: SINGLE-STORE-PER-SECTOR publish — stage the block's tagged 8x32
// publish tile in LDS (+1 barrier), then wave 0 alone stores 64 coalesced
// u64s: each sector written completely by 8 adjacent lanes in ONE
// wave-instruction -> ONE invalidation event per sector per step; consumer
// converges in <=2 RTs by construction. Protocol bytes/order unchanged.
// Poison 0xAAAA has LSB 0 != first expected phase 1 -> no init required.
// Step: poll(h(t-1)) -> barrier -> h-MFMAs -> gates -> stage-publish ->
// barrier -> wave0 sector stores -> filler (x rotate/prefetch + x-MFMA) ->
// s_sleep(6) -> loop.
template <bool XA>
__global__ __launch_bounds__(256, 1)
void lstm_persistent(const int* __restrict__ ids,
                     const int* __restrict__ seq_len,
                     const float* __restrict__ emb,
                     const float* __restrict__ w_ih,
                     const float* __restrict__ w_hh,
                     const float* __restrict__ b_ih,
                     const float* __restrict__ b_hh,
                     float* __restrict__ out,
                     _Float16* __restrict__ h16,      // [2][128][512] fp16
                     _Float16* __restrict__ x_all,    // [T][128][128] fp16
                     int* __restrict__ bar)
{
    __shared__ __align__(16) char smem[LDS_BYTES];
    unsigned* hsu = (unsigned*)smem;
    _Float16* hsh = (_Float16*)smem;
    float*    gs  = (float*)(smem + GOFF);
    unsigned short* pub = (unsigned short*)(smem + PUB_OFF);

    const int tid  = threadIdx.x;
    const int lane = tid & 63;
    const int wv   = tid >> 6;
    const int team = blockIdx.x & 15;
    const int p    = blockIdx.x >> 4;
    const int rowbase   = team * 8;
    const int unit_base = p * 32 + wv * 8;

    const int col  = lane & 15;   // MFMA n / C col
    const int kq   = lane >> 4;   // MFMA k-quad
    const int arow = lane & 7;    // A row (rows 8..15 duplicate 0..7)
    const int my_row  = lane >> 3;
    const int my_unit = unit_base + (lane & 7);

    if (XA) {
        // ---- phase 0: gather x_all[t][b][:] = fp16(emb[ids[t][b]][:]) ----
        for (int pair = blockIdx.x * 256 + tid; pair < TSEQ * BATCH;
             pair += 256 * 256) {
            const float* src = emb + (size_t)ids[pair] * DIN;   // pair = t*128+b
            _Float16* dst = x_all + (size_t)pair * DIN;
#pragma unroll
            for (int k = 0; k < 16; ++k) {
                float4v a = *(const float4v*)(src + k * 8);
                float4v c = *(const float4v*)(src + k * 8 + 4);
                *(half8*)(dst + k * 8) = cvt8(a, c);
            }
        }
        // ---- one-time grid barrier (full release/acquire, only here) ----
        __threadfence();
        __syncthreads();
        if (tid == 0) {
            __hip_atomic_fetch_add(bar, 1, __ATOMIC_RELEASE,
                                   __HIP_MEMORY_SCOPE_AGENT);
            int g = 0;
            while (__hip_atomic_load(bar, __ATOMIC_ACQUIRE,
                                     __HIP_MEMORY_SCOPE_AGENT) < 256
                   && ++g < (1 << 26)) { }
        }
        __syncthreads();
        __threadfence();
    }

    int tmax = 0, my_tstar = 0;
    for (int r = 0; r < 8; ++r) {
        int s  = seq_len[rowbase + r];
        int ts = (s > 0) ? (s - 1) : 0;
        if (r == my_row) my_tstar = ts;
        tmax = (ts > tmax) ? ts : tmax;
    }

    // ---- weight fragments -> VGPRs (fp32 -> fp16), once ----
    const int wrow0 = (col & 3) * HID + unit_base + (col >> 2);
    const int wrow1 = (col & 3) * HID + unit_base + 4 + (col >> 2);
    const float bias0 = b_ih[wrow0] + b_hh[wrow0];
    const float bias1 = b_ih[wrow1] + b_hh[wrow1];

    half8 whhf0[16], whhf1[16];
#pragma unroll
    for (int kt = 0; kt < 16; ++kt) {
        const float* s0 = w_hh + (size_t)wrow0 * HID + kt * 32 + kq * 8;
        const float* s1 = w_hh + (size_t)wrow1 * HID + kt * 32 + kq * 8;
        whhf0[kt] = cvt8(*(const float4v*)s0, *(const float4v*)(s0 + 4));
        whhf1[kt] = cvt8(*(const float4v*)s1, *(const float4v*)(s1 + 4));
    }
    half8 wihf0[4], wihf1[4];
#pragma unroll
    for (int kt = 0; kt < 4; ++kt) {
        const float* s0 = w_ih + (size_t)wrow0 * DIN + kt * 32 + kq * 8;
        const float* s1 = w_ih + (size_t)wrow1 * DIN + kt * 32 + kq * 8;
        wihf0[kt] = cvt8(*(const float4v*)s0, *(const float4v*)(s0 + 4));
        wihf1[kt] = cvt8(*(const float4v*)s1, *(const float4v*)(s1 + 4));
    }

    float c_state = 0.0f;
    const int crow = tid >> 5;    // poll/staging: row 0..7, 32 threads/row
    const int coff = tid & 31;    // thread polls u64s {coff + 32j}, j=0..3

    // ---- x fragment pipeline ----
    half8 xf[4], xn[4];
    if (XA) {
        const _Float16* x0 = x_all + ((size_t)0 * BATCH + rowbase + arow) * DIN;
        const int t1 = (tmax > 0) ? 1 : 0;
        const _Float16* x1 = x_all + ((size_t)t1 * BATCH + rowbase + arow) * DIN;
#pragma unroll
        for (int kt = 0; kt < 4; ++kt) {
            xf[kt] = *(const half8*)(x0 + kt * 32 + kq * 8);
            xn[kt] = *(const half8*)(x1 + kt * 32 + kq * 8);
        }
    } else {
        const int id0 = ids[rowbase + arow];
        const float* xrow = emb + (size_t)id0 * DIN;
#pragma unroll
        for (int kt = 0; kt < 4; ++kt) {
            const float* s = xrow + kt * 32 + kq * 8;
            xf[kt] = cvt8(*(const float4v*)s, *(const float4v*)(s + 4));
        }
    }

    // ---- acc(0) = bias + x(0) @ Wih, spread over 8 chains (a..d x 2) ----
    float4v a0 = {bias0, bias0, bias0, bias0}, b0 = {0,0,0,0}, c0 = {0,0,0,0}, d0 = {0,0,0,0};
    float4v a1 = {bias1, bias1, bias1, bias1}, b1 = {0,0,0,0}, c1 = {0,0,0,0}, d1 = {0,0,0,0};
    a0 = __builtin_amdgcn_mfma_f32_16x16x32_f16(xf[0], wihf0[0], a0, 0, 0, 0);
    b0 = __builtin_amdgcn_mfma_f32_16x16x32_f16(xf[1], wihf0[1], b0, 0, 0, 0);
    c0 = __builtin_amdgcn_mfma_f32_16x16x32_f16(xf[2], wihf0[2], c0, 0, 0, 0);
    d0 = __builtin_amdgcn_mfma_f32_16x16x32_f16(xf[3], wihf0[3], d0, 0, 0, 0);
    a1 = __builtin_amdgcn_mfma_f32_16x16x32_f16(xf[0], wihf1[0], a1, 0, 0, 0);
    b1 = __builtin_amdgcn_mfma_f32_16x16x32_f16(xf[1], wihf1[1], b1, 0, 0, 0);
    c1 = __builtin_amdgcn_mfma_f32_16x16x32_f16(xf[2], wihf1[2], c1, 0, 0, 0);
    d1 = __builtin_amdgcn_mfma_f32_16x16x32_f16(xf[3], wihf1[3], d1, 0, 0, 0);

    const u64 LSBM = 0x0001000100010001ull;

    for (int t = 0; t <= tmax; ++t) {
        const int bs = t & 1;    // LDS h-tile buffer for this step
        int id_next = 0;
        if (!XA) {
            const int tn = (t < tmax) ? (t + 1) : t;
            id_next = ids[tn * BATCH + rowbase + arow];
        }

        if (t > 0) {
            // ---- poll teammates' phase-tagged fp16 h (poll IS the load) ----
            const u64* rowp = (const u64*)(h16
                + (size_t)((t + 1) & 1) * BATCH * HID + (rowbase + crow) * HID);
            const u64 want = ((((t - 1) >> 1) & 1) ^ 1) ? LSBM : 0ull;
            unsigned* dstw = hsu + bs * HBUF_WORDS + crow * HW_STRIDE + 2 * coff;
            u64 v[4];
            unsigned pending = 0xF;
#pragma unroll
            for (int j = 0; j < 4; ++j)
                v[j] = __hip_atomic_load(rowp + coff + 32 * j,
                                         __ATOMIC_RELAXED, __HIP_MEMORY_SCOPE_AGENT);
#pragma unroll
            for (int j = 0; j < 4; ++j) {
                if (((v[j] ^ want) & LSBM) == 0) {
                    *(u64*)(dstw + 64 * j) = v[j];
                    pending &= ~(1u << j);
                }
            }
            int round = 0, guard = 0;
            while (pending) {
#pragma unroll
                for (int j = 0; j < 4; ++j) {
                    if (pending & (1u << j)) {
                        u64 x = __hip_atomic_load(rowp + coff + 32 * j,
                                                  __ATOMIC_RELAXED,
                                                  __HIP_MEMORY_SCOPE_AGENT);
                        if (((x ^ want) & LSBM) == 0) {
                            *(u64*)(dstw + 64 * j) = x;
                            pending &= ~(1u << j);
                        }
                    }
                }
                if (!pending) break;
                if (++round >= 3) __builtin_amdgcn_s_sleep(1);
                if (++guard > (1 << 20)) break;   // anti-hang safety valve
            }
        }
        __syncthreads();   // poll barrier (h-tile staged for all waves)

        float4v xraw[8];
        if (!XA) {
            // fallback: issue emb(t+1) raw loads here (h-MFMA shadow)
            const float* xrow = emb + (size_t)id_next * DIN;
#pragma unroll
            for (int kt = 0; kt < 4; ++kt) {
                xraw[2 * kt]     = *(const float4v*)(xrow + kt * 32 + kq * 8);
                xraw[2 * kt + 1] = *(const float4v*)(xrow + kt * 32 + kq * 8 + 4);
            }
        }

        if (t > 0) {
            // ---- h MFMAs: 16 kt over 8 chains (dependent depth 4) ----
            const _Float16* hb = hsh + bs * HBUF_WORDS * 2;
#pragma unroll
            for (int kt = 0; kt < 16; ++kt) {
                half8 af = *(const half8*)(hb + arow * (HW_STRIDE * 2) + kt * 32 + kq * 8);
                switch (kt & 3) {
                case 0:
                    a0 = __builtin_amdgcn_mfma_f32_16x16x32_f16(af, whhf0[kt], a0, 0, 0, 0);
                    a1 = __builtin_amdgcn_mfma_f32_16x16x32_f16(af, whhf1[kt], a1, 0, 0, 0);
                    break;
                case 1:
                    b0 = __builtin_amdgcn_mfma_f32_16x16x32_f16(af, whhf0[kt], b0, 0, 0, 0);
                    b1 = __builtin_amdgcn_mfma_f32_16x16x32_f16(af, whhf1[kt], b1, 0, 0, 0);
                    break;
                case 2:
                    c0 = __builtin_amdgcn_mfma_f32_16x16x32_f16(af, whhf0[kt], c0, 0, 0, 0);
                    c1 = __builtin_amdgcn_mfma_f32_16x16x32_f16(af, whhf1[kt], c1, 0, 0, 0);
                    break;
                default:
                    d0 = __builtin_amdgcn_mfma_f32_16x16x32_f16(af, whhf0[kt], d0, 0, 0, 0);
                    d1 = __builtin_amdgcn_mfma_f32_16x16x32_f16(af, whhf1[kt], d1, 0, 0, 0);
                }
            }
        }
        const float4v g0 = (a0 + b0) + (c0 + d0);
        const float4v g1 = (a1 + b1) + (c1 + d1);

        // ---- regroup i,f,g,o per (row,unit) via per-wave LDS scratch ----
        float* gw = gs + wv * 256;
        if (lane < 32) {
            const int grow = (lane >> 4) * 4;
#pragma unroll
            for (int r = 0; r < 4; ++r) {
                gw[(grow + r) * 32 + col]      = g0[r];
                gw[(grow + r) * 32 + 16 + col] = g1[r];
            }
        }
        const float4v g4 = *(const float4v*)(gw + my_row * 32 + (lane & 7) * 4);

        const float i_s = sigm(g4[0]);
        const float f_s = sigm(g4[1]);
        const float g_t = tanh_fast(g4[2]);
        const float o_s = sigm(g4[3]);
        c_state = f_s * c_state + i_s * g_t;
        const float hn = o_s * tanh_fast(c_state);

        if (t == my_tstar)
            out[(rowbase + my_row) * HID + my_unit] = c_state;

        // ---- publish h, SINGLE STORE PER SECTOR: stage tagged fp16 in the
        //      block's LDS pub tile, barrier, then wave 0 stores 64 coalesced
        //      u64s (each 64B sector = one row x this CU's 32 units written
        //      completely by 8 adjacent lanes in one wave-instruction) ----
        {
            const unsigned pub_phase = (((unsigned)t >> 1) & 1u) ^ 1u;
            unsigned short hb16 = __builtin_bit_cast(unsigned short, (_Float16)hn);
            hb16 = (unsigned short)((hb16 & 0xFFFEu) | pub_phase);
            pub[my_row * 32 + wv * 8 + (lane & 7)] = hb16;
        }
        __syncthreads();   // publish-staging barrier
        if (tid < 64) {
            const int r = tid >> 3, seg = tid & 7;
            const u64 pk = *(const u64*)(pub + r * 32 + seg * 4);
            __hip_atomic_store((u64*)((unsigned short*)h16
                                   + (size_t)(t & 1) * BATCH * HID
                                   + (rowbase + r) * HID + p * 32) + seg,
                               pk, __ATOMIC_RELAXED, __HIP_MEMORY_SCOPE_AGENT);
        }

        // ---- filler between publish and next poll: x pipeline + x-MFMA(t+1)
        //      then a tuned s_sleep so poll round-0 samples past producer
        //      visibility ----
        if (XA) {
#pragma unroll
            for (int kt = 0; kt < 4; ++kt) xf[kt] = xn[kt];
            const int t2 = (t + 2 <= tmax) ? (t + 2) : tmax;
            const _Float16* xs2 = x_all + ((size_t)t2 * BATCH + rowbase + arow) * DIN;
#pragma unroll
            for (int kt = 0; kt < 4; ++kt)
                xn[kt] = *(const half8*)(xs2 + kt * 32 + kq * 8);
        } else {
#pragma unroll
            for (int kt = 0; kt < 4; ++kt)
                xf[kt] = cvt8(xraw[2 * kt], xraw[2 * kt + 1]);
        }

        a0 = (float4v){bias0, bias0, bias0, bias0}; b0 = (float4v){0,0,0,0};
        c0 = (float4v){0,0,0,0};                    d0 = (float4v){0,0,0,0};
        a1 = (float4v){bias1, bias1, bias1, bias1}; b1 = (float4v){0,0,0,0};
        c1 = (float4v){0,0,0,0};                    d1 = (float4v){0,0,0,0};
        a0 = __builtin_amdgcn_mfma_f32_16x16x32_f16(xf[0], wihf0[0], a0, 0, 0, 0);
        b0 = __builtin_amdgcn_mfma_f32_16x16x32_f16(xf[1], wihf0[1], b0, 0, 0, 0);
        c0 = __builtin_amdgcn_mfma_f32_16x16x32_f16(xf[2], wihf0[2], c0, 0, 0, 0);
        d0 = __builtin_amdgcn_mfma_f32_16x16x32_f16(xf[3], wihf0[3], d0, 0, 0, 0);
        a1 = __builtin_amdgcn_mfma_f32_16x16x32_f16(xf[0], wihf1[0], a1, 0, 0, 0);
        b1 = __builtin_amdgcn_mfma_f32_16x16x32_f16(xf[1], wihf1[1], b1, 0, 0, 0);
        c1 = __builtin_amdgcn_mfma_f32_16x16x32_f16(xf[2], wihf1[2], c1, 0, 0, 0);
        d1 = __builtin_amdgcn_mfma_f32_16x16x32_f16(xf[3], wihf1[3], d1, 0, 0, 0);

        // tuned pre-poll delay: ~384 cyc (producer store->IF visibility + skew)
        __builtin_amdgcn_s_sleep(6);
    }
}

extern "C" void kernel_launch(void* const* d_in, const int* in_sizes, int n_in,
                              void* d_out, int out_size, void* d_ws, size_t ws_size,
                              hipStream_t stream)
{
    const int*   ids  = (const int*)d_in[0];
    const int*   slen = (const int*)d_in[1];
    const float* emb  = (const float*)d_in[2];
    const float* wih  = (const float*)d_in[3];
    const float* whh  = (const float*)d_in[4];
    const float* bih  = (const float*)d_in[5];
    const float* bhh  = (const float*)d_in[6];
    float* out = (float*)d_out;

    _Float16* h16   = (_Float16*)((char*)d_ws + WS_H16_OFF);
    int*      bar   = (int*)((char*)d_ws + WS_BAR_OFF);
    _Float16* x_all = (_Float16*)((char*)d_ws + WS_XALL_OFF);

    if (ws_size >= WS_NEED) {
        hipMemsetAsync(bar, 0, sizeof(int), stream);
        hipLaunchKernelGGL((lstm_persistent<true>), dim3(256), dim3(256), 0, stream,
                           ids, slen, emb, wih, whh, bih, bhh, out,
                           h16, x_all, bar);
    } else {
        hipLaunchKernelGGL((lstm_persistent<false>), dim3(256), dim3(256), 0, stream,
                           ids, slen, emb, wih, whh, bih, bhh, out,
                           h16, x_all, bar);
    }
}